// Round 2
// baseline (1727.886 us; speedup 1.0000x reference)
//
#include <hip/hip_runtime.h>
#include <hip/hip_bf16.h>

// IndRNN forward, 2 layers.
// B=64 T=2048 I=256 H=512.
// Structure:
//   GEMM0: pre0 = x @ w_ih0^T + b_ih0      (M=131072, K=256, N=512) -> d_ws
//   SCAN0: in-place diagonal scan over T on d_ws
//   GEMM1: pre1 = out0 @ w_ih1^T + b_ih1   (M=131072, K=512, N=512) -> d_out
//   SCAN1: in-place scan on d_out
// d_ws requirement: 64*2048*512*4 = 256 MiB.

#define BB 64
#define TT 2048
#define II 256
#define HH 512
#define MM (BB * TT)  // 131072

// ---------------------------------------------------------------------------
// fp32 tiled GEMM: C[M x 512] = A[M x K] * W[512 x K]^T + bias
// 128x128 tile, BK=16, 256 threads, 8x8 micro-tile per thread.
// LDS stored K-major (As[k][m]) so compute reads are contiguous float4.
// ---------------------------------------------------------------------------
template <int K>
__global__ __launch_bounds__(256) void gemm_bias(const float* __restrict__ A,
                                                 const float* __restrict__ W,
                                                 const float* __restrict__ bias,
                                                 float* __restrict__ C) {
  constexpr int BM = 128, BN = 128, BK = 16;
  __shared__ float As[BK][BM];
  __shared__ float Ws[BK][BN];

  const int tid = threadIdx.x;
  const int m0 = blockIdx.y * BM;
  const int n0 = blockIdx.x * BN;
  const int tx = tid & 15;   // 0..15 (col group)
  const int ty = tid >> 4;   // 0..15 (row group)

  float acc[8][8];
#pragma unroll
  for (int i = 0; i < 8; ++i)
#pragma unroll
    for (int j = 0; j < 8; ++j) acc[i][j] = 0.f;

  for (int kt = 0; kt < K; kt += BK) {
    // ---- stage A and W tiles (each: 128 rows x 16 k = 512 float4, 2/thread)
#pragma unroll
    for (int s = 0; s < 2; ++s) {
      const int idx = tid * 2 + s;       // 0..511
      const int row = idx >> 2;          // 0..127
      const int kg = idx & 3;            // 0..3  (float4 group along k)
      const float4 va = *(const float4*)(A + (size_t)(m0 + row) * K + kt + kg * 4);
      As[kg * 4 + 0][row] = va.x;
      As[kg * 4 + 1][row] = va.y;
      As[kg * 4 + 2][row] = va.z;
      As[kg * 4 + 3][row] = va.w;
      const float4 vw = *(const float4*)(W + (size_t)(n0 + row) * K + kt + kg * 4);
      Ws[kg * 4 + 0][row] = vw.x;
      Ws[kg * 4 + 1][row] = vw.y;
      Ws[kg * 4 + 2][row] = vw.z;
      Ws[kg * 4 + 3][row] = vw.w;
    }
    __syncthreads();

    // ---- compute
#pragma unroll
    for (int k = 0; k < BK; ++k) {
      const float4 a0 = *(const float4*)&As[k][ty * 4];
      const float4 a1 = *(const float4*)&As[k][ty * 4 + 64];
      const float4 b0 = *(const float4*)&Ws[k][tx * 4];
      const float4 b1 = *(const float4*)&Ws[k][tx * 4 + 64];
      const float a[8] = {a0.x, a0.y, a0.z, a0.w, a1.x, a1.y, a1.z, a1.w};
      const float b[8] = {b0.x, b0.y, b0.z, b0.w, b1.x, b1.y, b1.z, b1.w};
#pragma unroll
      for (int i = 0; i < 8; ++i)
#pragma unroll
        for (int j = 0; j < 8; ++j) acc[i][j] = fmaf(a[i], b[j], acc[i][j]);
    }
    __syncthreads();
  }

  // ---- epilogue: + bias, float4 stores
  const float4 blo = *(const float4*)(bias + n0 + tx * 4);
  const float4 bhi = *(const float4*)(bias + n0 + 64 + tx * 4);
  const float bl[4] = {blo.x, blo.y, blo.z, blo.w};
  const float bh[4] = {bhi.x, bhi.y, bhi.z, bhi.w};
#pragma unroll
  for (int i = 0; i < 8; ++i) {
    const int m = m0 + ((i < 4) ? (ty * 4 + i) : (64 + ty * 4 + (i - 4)));
    float4 lo, hi;
    lo.x = acc[i][0] + bl[0];
    lo.y = acc[i][1] + bl[1];
    lo.z = acc[i][2] + bl[2];
    lo.w = acc[i][3] + bl[3];
    hi.x = acc[i][4] + bh[0];
    hi.y = acc[i][5] + bh[1];
    hi.z = acc[i][6] + bh[2];
    hi.w = acc[i][7] + bh[3];
    *(float4*)(C + (size_t)m * HH + n0 + tx * 4) = lo;
    *(float4*)(C + (size_t)m * HH + n0 + 64 + tx * 4) = hi;
  }
}

// ---------------------------------------------------------------------------
// In-place diagonal scan: for each (b,h): h_t = relu(pre_t + w[h]*h_{t-1}).
// One thread per (b,h) column; double-buffered U=32 prefetch to keep ~32
// loads in flight per thread (latency-bound regime: only 512 waves total).
// Consecutive threads -> consecutive h -> coalesced 256B/wave per t-step.
// ---------------------------------------------------------------------------
__global__ __launch_bounds__(256) void indrnn_scan(float* __restrict__ buf,
                                                   const float* __restrict__ w_hh) {
  const int gid = blockIdx.x * 256 + threadIdx.x;  // 0 .. B*H-1
  const int b = gid >> 9;    // /512
  const int h = gid & 511;
  const float w = w_hh[h];
  float* p = buf + (size_t)b * TT * HH + h;

  constexpr int U = 32;
  float cur[U], nxt[U];
  float hv = 0.f;

#pragma unroll
  for (int u = 0; u < U; ++u) cur[u] = p[(size_t)u * HH];

  for (int t0 = 0; t0 < TT; t0 += U) {
    const bool more = (t0 + U) < TT;
    if (more) {
#pragma unroll
      for (int u = 0; u < U; ++u) nxt[u] = p[(size_t)(t0 + U + u) * HH];
    }
#pragma unroll
    for (int u = 0; u < U; ++u) {
      hv = fmaxf(fmaf(w, hv, cur[u]), 0.f);
      cur[u] = hv;
    }
#pragma unroll
    for (int u = 0; u < U; ++u) p[(size_t)(t0 + u) * HH] = cur[u];
    if (more) {
#pragma unroll
      for (int u = 0; u < U; ++u) cur[u] = nxt[u];
    }
  }
}

extern "C" void kernel_launch(void* const* d_in, const int* in_sizes, int n_in,
                              void* d_out, int out_size, void* d_ws, size_t ws_size,
                              hipStream_t stream) {
  const float* x     = (const float*)d_in[0];  // (B,T,I)
  const float* w_ih0 = (const float*)d_in[1];  // (H,I)
  const float* w_hh0 = (const float*)d_in[2];  // (H)
  const float* b_ih0 = (const float*)d_in[3];  // (H)
  const float* w_ih1 = (const float*)d_in[4];  // (H,H)
  const float* w_hh1 = (const float*)d_in[5];  // (H)
  const float* b_ih1 = (const float*)d_in[6];  // (H)
  float* out = (float*)d_out;                  // (B,T,H)
  float* ws  = (float*)d_ws;                   // needs 256 MiB

  const dim3 blk(256);
  const dim3 grid(HH / 128, MM / 128);  // (4, 1024), blockIdx.x fastest -> A-tile L2 reuse

  // Layer 0
  gemm_bias<II><<<grid, blk, 0, stream>>>(x, w_ih0, b_ih0, ws);
  indrnn_scan<<<(BB * HH) / 256, 256, 0, stream>>>(ws, w_hh0);
  // Layer 1
  gemm_bias<HH><<<grid, blk, 0, stream>>>(ws, w_ih1, b_ih1, out);
  indrnn_scan<<<(BB * HH) / 256, 256, 0, stream>>>(out, w_hh1);
}

// Round 4
// 1022.432 us; speedup vs baseline: 1.6900x; 1.6900x over previous
//
#include <hip/hip_runtime.h>
#include <hip/hip_bf16.h>

// IndRNN forward, 2 layers. B=64 T=2048 I=256 H=512.
//   GEMM0: pre0 = x @ w_ih0^T + b_ih0 (M=131072,K=256,N=512) -> d_ws   [bf16x3 MFMA]
//   SCAN0: in-place diagonal scan over T on d_ws
//   GEMM1: pre1 = out0 @ w_ih1^T + b_ih1 (K=512) -> d_out              [bf16x3 MFMA]
//   SCAN1: in-place scan on d_out
// GEMMs: 3-term bf16 split (Ah*Wh + Ah*Wl + Al*Wh) on v_mfma_f32_16x16x32_bf16.
// Expected absmax vs fp32 ref ~1e-5.

#define BB 64
#define TT 2048
#define II 256
#define HH 512
#define MM (BB * TT)  // 131072

typedef __attribute__((ext_vector_type(8))) short bf16x8;
typedef __attribute__((ext_vector_type(4))) float f32x4;

__device__ inline unsigned short bf16_rne(float f) {
  unsigned u = __builtin_bit_cast(unsigned, f);
  u += 0x7FFFu + ((u >> 16) & 1u);
  return (unsigned short)(u >> 16);
}
__device__ inline float bf16_val(unsigned short h) {
  unsigned u = ((unsigned)h) << 16;
  return __builtin_bit_cast(float, u);
}

// ---------------------------------------------------------------------------
// bf16x3 MFMA GEMM: C[M x 512] = A[M x K] * W[512 x K]^T + bias
// 128x128 tile, BK=32, 256 threads (4 waves, 2x2 of 64x64 each).
// LDS: hi/lo bf16 tiles, row-major [row][k], row stride padded to 40 bf16
// (80 B = 16B-aligned rows, 2-way max read conflict per quarter-wave).
// XCD-co-locating bid swizzle: the 4 N-blocks sharing an A-panel get bids
// spaced 8 apart -> same XCD -> A fetched from HBM once (FETCH ~= 256MB).
// ---------------------------------------------------------------------------
template <int K>
__global__ __launch_bounds__(256) void gemm_mfma(const float* __restrict__ A,
                                                 const float* __restrict__ W,
                                                 const float* __restrict__ bias,
                                                 float* __restrict__ C) {
  constexpr int BM = 128, BN = 128, BK = 32;
  constexpr int LDT = 40;  // padded LDS row stride in bf16 elements
  __shared__ unsigned short Ah[BM * LDT], Al[BM * LDT];
  __shared__ unsigned short Bh[BN * LDT], Bl[BN * LDT];

  // ---- tile mapping with XCD co-location (8 XCDs, 1024 M-blocks, 4 N-blocks)
  const int bid = blockIdx.x;              // 0..4095
  const int xcd = bid & 7;
  const int local = bid >> 3;              // 0..511
  const int mb = xcd * (MM / BM / 8) + (local >> 2);
  const int nb = local & 3;
  const int m0 = mb * BM, n0 = nb * BN;

  const int tid = threadIdx.x;
  const int lane = tid & 63;
  const int wave = tid >> 6;
  const int wr = wave >> 1, wc = wave & 1;   // 2x2 wave grid
  const int lrow = lane & 15, lkg = lane >> 4;

  f32x4 acc[4][4] = {};

  // staging: thread covers row srow, 4 consecutive float4 at float4-index skq
  const int srow = tid >> 1;
  const int skq = (tid & 1) * 4;

  for (int kt = 0; kt < K; kt += BK) {
    // ---- issue global loads (no LDS dep; overlaps the barrier wait)
    const float4* Aq = (const float4*)(A + (size_t)(m0 + srow) * K + kt) + skq;
    const float4* Wq = (const float4*)(W + (size_t)(n0 + srow) * K + kt) + skq;
    float4 av[4], wv[4];
#pragma unroll
    for (int s = 0; s < 4; ++s) { av[s] = Aq[s]; wv[s] = Wq[s]; }

    __syncthreads();  // previous compute's LDS reads done

    // ---- split to hi/lo bf16 and store to LDS
#pragma unroll
    for (int s = 0; s < 4; ++s) {
      const int kk = (skq + s) * 4;
      const float fa[4] = {av[s].x, av[s].y, av[s].z, av[s].w};
      const float fw[4] = {wv[s].x, wv[s].y, wv[s].z, wv[s].w};
      ushort4 ah, al, wh, wl;
      unsigned short* pah = (unsigned short*)&ah;
      unsigned short* pal = (unsigned short*)&al;
      unsigned short* pwh = (unsigned short*)&wh;
      unsigned short* pwl = (unsigned short*)&wl;
#pragma unroll
      for (int e = 0; e < 4; ++e) {
        const unsigned short h1 = bf16_rne(fa[e]);
        pah[e] = h1;
        pal[e] = bf16_rne(fa[e] - bf16_val(h1));
        const unsigned short h2 = bf16_rne(fw[e]);
        pwh[e] = h2;
        pwl[e] = bf16_rne(fw[e] - bf16_val(h2));
      }
      *(ushort4*)&Ah[srow * LDT + kk] = ah;
      *(ushort4*)&Al[srow * LDT + kk] = al;
      *(ushort4*)&Bh[srow * LDT + kk] = wh;
      *(ushort4*)&Bl[srow * LDT + kk] = wl;
    }
    __syncthreads();  // tile ready

    // ---- fragments: A[row=lrow(+16i)][k = lkg*8 .. +8] contiguous bf16x8
    bf16x8 afh[4], afl[4], bfh[4], bfl[4];
#pragma unroll
    for (int i = 0; i < 4; ++i) {
      const int ar = wr * 64 + i * 16 + lrow;
      afh[i] = *(const bf16x8*)&Ah[ar * LDT + lkg * 8];
      afl[i] = *(const bf16x8*)&Al[ar * LDT + lkg * 8];
      const int br = wc * 64 + i * 16 + lrow;
      bfh[i] = *(const bf16x8*)&Bh[br * LDT + lkg * 8];
      bfl[i] = *(const bf16x8*)&Bl[br * LDT + lkg * 8];
    }
#pragma unroll
    for (int i = 0; i < 4; ++i)
#pragma unroll
      for (int j = 0; j < 4; ++j) {
        acc[i][j] = __builtin_amdgcn_mfma_f32_16x16x32_bf16(afh[i], bfh[j], acc[i][j], 0, 0, 0);
        acc[i][j] = __builtin_amdgcn_mfma_f32_16x16x32_bf16(afh[i], bfl[j], acc[i][j], 0, 0, 0);
        acc[i][j] = __builtin_amdgcn_mfma_f32_16x16x32_bf16(afl[i], bfh[j], acc[i][j], 0, 0, 0);
      }
  }

  // ---- epilogue: C/D layout col=lane&15, row=(lane>>4)*4+reg (m89-verified)
  const int rb = (lane >> 4) * 4;
#pragma unroll
  for (int j = 0; j < 4; ++j) {
    const int col = n0 + wc * 64 + j * 16 + lrow;
    const float bv = bias[col];
#pragma unroll
    for (int i = 0; i < 4; ++i) {
      const int row0 = m0 + wr * 64 + i * 16 + rb;
#pragma unroll
      for (int r = 0; r < 4; ++r)
        C[(size_t)(row0 + r) * HH + col] = acc[i][j][r] + bv;
    }
  }
}

// ---------------------------------------------------------------------------
// In-place diagonal scan: h_t = relu(pre_t + w[h]*h_{t-1}) per (b,h) column.
// 32768 threads (512 waves, ~2/CU) -> latency-bound; U=64 double-buffered
// prefetch keeps ~8MB in flight (> BW*latency ~2.4MB) -> BW-bound regime.
// ---------------------------------------------------------------------------
__global__ __launch_bounds__(256, 1) void indrnn_scan(float* __restrict__ buf,
                                                      const float* __restrict__ w_hh) {
  const int gid = blockIdx.x * 256 + threadIdx.x;  // 0..B*H-1
  const int b = gid >> 9;
  const int h = gid & 511;
  const float w = w_hh[h];
  float* p = buf + (size_t)b * TT * HH + h;

  constexpr int U = 64;
  float cur[U], nxt[U];
  float hv = 0.f;

#pragma unroll
  for (int u = 0; u < U; ++u) cur[u] = p[(size_t)u * HH];

  for (int t0 = 0; t0 < TT; t0 += U) {
    const bool more = (t0 + U) < TT;
    if (more) {
#pragma unroll
      for (int u = 0; u < U; ++u) nxt[u] = p[(size_t)(t0 + U + u) * HH];
    }
#pragma unroll
    for (int u = 0; u < U; ++u) {
      hv = fmaxf(fmaf(w, hv, cur[u]), 0.f);
      cur[u] = hv;
    }
#pragma unroll
    for (int u = 0; u < U; ++u) p[(size_t)(t0 + u) * HH] = cur[u];
    if (more) {
#pragma unroll
      for (int u = 0; u < U; ++u) cur[u] = nxt[u];
    }
  }
}

extern "C" void kernel_launch(void* const* d_in, const int* in_sizes, int n_in,
                              void* d_out, int out_size, void* d_ws, size_t ws_size,
                              hipStream_t stream) {
  const float* x     = (const float*)d_in[0];
  const float* w_ih0 = (const float*)d_in[1];
  const float* w_hh0 = (const float*)d_in[2];
  const float* b_ih0 = (const float*)d_in[3];
  const float* w_ih1 = (const float*)d_in[4];
  const float* w_hh1 = (const float*)d_in[5];
  const float* b_ih1 = (const float*)d_in[6];
  float* out = (float*)d_out;
  float* ws  = (float*)d_ws;  // 256 MiB

  const int ntiles = (MM / 128) * (HH / 128);  // 4096

  gemm_mfma<II><<<ntiles, 256, 0, stream>>>(x, w_ih0, b_ih0, ws);
  indrnn_scan<<<(BB * HH) / 256, 256, 0, stream>>>(ws, w_hh0);
  gemm_mfma<HH><<<ntiles, 256, 0, stream>>>(ws, w_ih1, b_ih1, out);
  indrnn_scan<<<(BB * HH) / 256, 256, 0, stream>>>(out, w_hh1);
}

// Round 8
// 944.395 us; speedup vs baseline: 1.8296x; 1.0826x over previous
//
#include <hip/hip_runtime.h>
#include <hip/hip_bf16.h>

// IndRNN forward, 2 layers. B=64 T=2048 I=256 H=512.
// Tier A (ws >= 513.5MB):
//   CONV:  W0,W1 -> bf16 hi/lo tables (1.5MB)
//   GEMM0: pre0 = x @ W0^T + b0  (fp32 A converted in-kernel, W pre-converted) -> ws
//   SCAN0: diagonal scan, writes h as bf16 hi/lo (A1h,A1l) for GEMM1
//   GEMM1: pre1 = A1 @ W1^T + b1 (pure bf16 staging, zero conversion VALU) -> d_out
//   SCAN1: in-place scan on d_out (fp32)
// Tier B (small ws): round-4 GEMMs (in-kernel conversions) + new scans.
// Scan: 512 single-wave blocks (all CUs), global_load_lds staging, counted
// vmcnt(48) pipeline (3 chunks x 16 t in flight, never drain to 0).

#define BB 64
#define TT 2048
#define II 256
#define HH 512
#define MM (BB * TT)  // 131072

typedef __attribute__((ext_vector_type(8))) short bf16x8;
typedef __attribute__((ext_vector_type(4))) float f32x4;

__device__ inline unsigned short bf16_rne(float f) {
  unsigned u = __builtin_bit_cast(unsigned, f);
  u += 0x7FFFu + ((u >> 16) & 1u);
  return (unsigned short)(u >> 16);
}
__device__ inline float bf16_val(unsigned short h) {
  unsigned u = ((unsigned)h) << 16;
  return __builtin_bit_cast(float, u);
}

typedef __attribute__((address_space(1))) const void GASV;
typedef __attribute__((address_space(3))) void LASV;
__device__ inline void gload_lds4(const float* g, float* l) {
  __builtin_amdgcn_global_load_lds((GASV*)g, (LASV*)l, 4, 0, 0);
}

// ---------------------------------------------------------------------------
// bf16x3 MFMA GEMM: C[M x 512] = A[M x K] * W[512 x K]^T + bias
// 128x128 tile, BK=32, 4 waves (2x2 of 64x64). LDS rows padded to 40 bf16.
// MODE 0: A fp32 + W fp32 (both converted in-kernel)  [round-4 proven]
// MODE 1: A fp32 (converted in-kernel) + W pre-converted bf16 hi/lo
// MODE 2: A bf16 hi/lo + W bf16 hi/lo (zero conversion VALU)
// XCD-co-locating bid swizzle (A-panel sharers land on one XCD).
// ---------------------------------------------------------------------------
template <int K, int MODE>
__global__ __launch_bounds__(256) void gemm_mfma(
    const float* __restrict__ Af, const unsigned short* __restrict__ Ahg,
    const unsigned short* __restrict__ Alg, const float* __restrict__ Wf,
    const unsigned short* __restrict__ Whg, const unsigned short* __restrict__ Wlg,
    const float* __restrict__ bias, float* __restrict__ C) {
  constexpr int BM = 128, BN = 128, BK = 32;
  constexpr int LDT = 40;  // padded LDS row stride (80B, 16B-aligned, 2-way max)
  __shared__ unsigned short Ah[BM * LDT], Al[BM * LDT];
  __shared__ unsigned short Bh[BN * LDT], Bl[BN * LDT];

  const int bid = blockIdx.x;  // 0..4095
  const int xcd = bid & 7;
  const int local = bid >> 3;
  const int mb = xcd * (MM / BM / 8) + (local >> 2);
  const int nb = local & 3;
  const int m0 = mb * BM, n0 = nb * BN;

  const int tid = threadIdx.x;
  const int lane = tid & 63;
  const int wave = tid >> 6;
  const int wr = wave >> 1, wc = wave & 1;
  const int lrow = lane & 15, lkg = lane >> 4;

  f32x4 acc[4][4] = {};

  const int srow = tid >> 1;          // staged row (0..127)
  const int skq = (tid & 1) * 4;      // float4 index (fp32 path)
  const int skq8 = (tid & 1) * 16;    // bf16 elem index (bf16 path)

  for (int kt = 0; kt < K; kt += BK) {
    // ---- global loads (issued before barrier; no LDS dependency)
    float4 av[4], wv[4];
    bf16x8 a8[4], w8[4];
    if constexpr (MODE == 2) {
      const size_t ro = (size_t)(m0 + srow) * K + kt + skq8;
      a8[0] = *(const bf16x8*)(Ahg + ro);
      a8[1] = *(const bf16x8*)(Ahg + ro + 8);
      a8[2] = *(const bf16x8*)(Alg + ro);
      a8[3] = *(const bf16x8*)(Alg + ro + 8);
    } else {
      const float4* Aq = (const float4*)(Af + (size_t)(m0 + srow) * K + kt) + skq;
#pragma unroll
      for (int s = 0; s < 4; ++s) av[s] = Aq[s];
    }
    if constexpr (MODE >= 1) {
      const size_t ro = (size_t)(n0 + srow) * K + kt + skq8;
      w8[0] = *(const bf16x8*)(Whg + ro);
      w8[1] = *(const bf16x8*)(Whg + ro + 8);
      w8[2] = *(const bf16x8*)(Wlg + ro);
      w8[3] = *(const bf16x8*)(Wlg + ro + 8);
    } else {
      const float4* Wq = (const float4*)(Wf + (size_t)(n0 + srow) * K + kt) + skq;
#pragma unroll
      for (int s = 0; s < 4; ++s) wv[s] = Wq[s];
    }

    __syncthreads();  // previous compute's LDS reads done

    // ---- A tile to LDS
    if constexpr (MODE == 2) {
      *(bf16x8*)&Ah[srow * LDT + skq8] = a8[0];
      *(bf16x8*)&Ah[srow * LDT + skq8 + 8] = a8[1];
      *(bf16x8*)&Al[srow * LDT + skq8] = a8[2];
      *(bf16x8*)&Al[srow * LDT + skq8 + 8] = a8[3];
    } else {
#pragma unroll
      for (int s = 0; s < 4; ++s) {
        const int kk = (skq + s) * 4;
        const float fa[4] = {av[s].x, av[s].y, av[s].z, av[s].w};
        ushort4 ah4, al4;
        unsigned short* pah = (unsigned short*)&ah4;
        unsigned short* pal = (unsigned short*)&al4;
#pragma unroll
        for (int e = 0; e < 4; ++e) {
          const unsigned short h1 = bf16_rne(fa[e]);
          pah[e] = h1;
          pal[e] = bf16_rne(fa[e] - bf16_val(h1));
        }
        *(ushort4*)&Ah[srow * LDT + kk] = ah4;
        *(ushort4*)&Al[srow * LDT + kk] = al4;
      }
    }
    // ---- W tile to LDS
    if constexpr (MODE >= 1) {
      *(bf16x8*)&Bh[srow * LDT + skq8] = w8[0];
      *(bf16x8*)&Bh[srow * LDT + skq8 + 8] = w8[1];
      *(bf16x8*)&Bl[srow * LDT + skq8] = w8[2];
      *(bf16x8*)&Bl[srow * LDT + skq8 + 8] = w8[3];
    } else {
#pragma unroll
      for (int s = 0; s < 4; ++s) {
        const int kk = (skq + s) * 4;
        const float fw[4] = {wv[s].x, wv[s].y, wv[s].z, wv[s].w};
        ushort4 wh4, wl4;
        unsigned short* pwh = (unsigned short*)&wh4;
        unsigned short* pwl = (unsigned short*)&wl4;
#pragma unroll
        for (int e = 0; e < 4; ++e) {
          const unsigned short h2 = bf16_rne(fw[e]);
          pwh[e] = h2;
          pwl[e] = bf16_rne(fw[e] - bf16_val(h2));
        }
        *(ushort4*)&Bh[srow * LDT + kk] = wh4;
        *(ushort4*)&Bl[srow * LDT + kk] = wl4;
      }
    }
    __syncthreads();  // tile ready

    // ---- fragments + MFMA (layout m89-verified; unchanged from round 4)
    bf16x8 afh[4], afl[4], bfh[4], bfl[4];
#pragma unroll
    for (int i = 0; i < 4; ++i) {
      const int ar = wr * 64 + i * 16 + lrow;
      afh[i] = *(const bf16x8*)&Ah[ar * LDT + lkg * 8];
      afl[i] = *(const bf16x8*)&Al[ar * LDT + lkg * 8];
      const int br = wc * 64 + i * 16 + lrow;
      bfh[i] = *(const bf16x8*)&Bh[br * LDT + lkg * 8];
      bfl[i] = *(const bf16x8*)&Bl[br * LDT + lkg * 8];
    }
#pragma unroll
    for (int i = 0; i < 4; ++i)
#pragma unroll
      for (int j = 0; j < 4; ++j) {
        acc[i][j] = __builtin_amdgcn_mfma_f32_16x16x32_bf16(afh[i], bfh[j], acc[i][j], 0, 0, 0);
        acc[i][j] = __builtin_amdgcn_mfma_f32_16x16x32_bf16(afh[i], bfl[j], acc[i][j], 0, 0, 0);
        acc[i][j] = __builtin_amdgcn_mfma_f32_16x16x32_bf16(afl[i], bfh[j], acc[i][j], 0, 0, 0);
      }
  }

  // ---- epilogue: C/D layout col=lane&15, row=(lane>>4)*4+reg
  const int rb = (lane >> 4) * 4;
#pragma unroll
  for (int j = 0; j < 4; ++j) {
    const int col = n0 + wc * 64 + j * 16 + lrow;
    const float bv = bias[col];
#pragma unroll
    for (int i = 0; i < 4; ++i) {
      const int row0 = m0 + wr * 64 + i * 16 + rb;
#pragma unroll
      for (int r = 0; r < 4; ++r)
        C[(size_t)(row0 + r) * HH + col] = acc[i][j][r] + bv;
    }
  }
}

// ---------------------------------------------------------------------------
// Diagonal scan, pipelined: h_t = relu(pre_t + w[h]*h_{t-1}) per (b,h) column.
// 512 single-wave blocks (64 consecutive h each; blocks never straddle b).
// global_load_lds stages 16-t chunks into 4 LDS slots; counted vmcnt(48)
// keeps 2-3 chunks of loads in flight across the whole scan (no full drain).
// SPLIT: store h as bf16 hi/lo (feeds GEMM1 MODE2); else fp32 (may alias pre).
// ---------------------------------------------------------------------------
template <bool SPLIT>
__global__ __launch_bounds__(64) void indrnn_scan2(
    const float* __restrict__ pre, const float* __restrict__ w_hh,
    float* __restrict__ outf, unsigned short* __restrict__ outh,
    unsigned short* __restrict__ outl) {
  constexpr int CH = 16, NCH = TT / CH, AHEAD = 3;
  __shared__ float lds[4 * CH * 64];
  const int lane = threadIdx.x;
  const int gid = blockIdx.x * 64 + lane;
  const int h = gid & (HH - 1);
  const size_t colbase = (size_t)(gid >> 9) * TT * HH + h;

  const float w = w_hh[h];
  float hv = 0.f;

  auto issue = [&](int c) {
    const float* g = pre + colbase + (size_t)(c * CH) * HH;
    float* l = &lds[(c & 3) * CH * 64];
#pragma unroll
    for (int tt = 0; tt < CH; ++tt) gload_lds4(g + (size_t)tt * HH, l + tt * 64);
  };

  issue(0);
  issue(1);
  issue(2);
  for (int c = 0; c < NCH; ++c) {
    if (c + AHEAD < NCH) issue(c + AHEAD);
    // chunk c's 16 loads are >= 3 issue-groups older than the newest 48 vmem
    // ops (vmcnt retires in order), so <=48 outstanding implies chunk c landed.
    asm volatile("s_waitcnt vmcnt(48)" ::: "memory");
    __builtin_amdgcn_sched_barrier(0);
    const float* l = &lds[(c & 3) * CH * 64];
#pragma unroll
    for (int tt = 0; tt < CH; ++tt) {
      const float p = l[tt * 64 + lane];
      hv = fmaxf(fmaf(w, hv, p), 0.f);
      const size_t gi = colbase + (size_t)(c * CH + tt) * HH;
      if constexpr (SPLIT) {
        const unsigned short hh = bf16_rne(hv);
        outh[gi] = hh;
        outl[gi] = bf16_rne(hv - bf16_val(hh));
      } else {
        outf[gi] = hv;
      }
    }
  }
}

// ---------------------------------------------------------------------------
__global__ __launch_bounds__(256) void convert_w(const float* __restrict__ W,
                                                 unsigned short* __restrict__ Wh,
                                                 unsigned short* __restrict__ Wl,
                                                 int n) {
  const int i = blockIdx.x * 256 + threadIdx.x;
  if (i < n) {
    const float f = W[i];
    const unsigned short hh = bf16_rne(f);
    Wh[i] = hh;
    Wl[i] = bf16_rne(f - bf16_val(hh));
  }
}

extern "C" void kernel_launch(void* const* d_in, const int* in_sizes, int n_in,
                              void* d_out, int out_size, void* d_ws, size_t ws_size,
                              hipStream_t stream) {
  const float* x     = (const float*)d_in[0];
  const float* w_ih0 = (const float*)d_in[1];
  const float* w_hh0 = (const float*)d_in[2];
  const float* b_ih0 = (const float*)d_in[3];
  const float* w_ih1 = (const float*)d_in[4];
  const float* w_hh1 = (const float*)d_in[5];
  const float* b_ih1 = (const float*)d_in[6];
  float* out = (float*)d_out;
  float* pre0 = (float*)d_ws;  // 256MB
  char* wsb = (char*)d_ws;

  const size_t OFF_A1H = 268435456ull;              // pre0 end
  const size_t OFF_A1L = OFF_A1H + 134217728ull;    // A1h end
  const size_t OFF_W0H = OFF_A1L + 134217728ull;    // 512MB
  const size_t OFF_W0L = OFF_W0H + 262144ull;
  const size_t OFF_W1H = OFF_W0L + 262144ull;
  const size_t OFF_W1L = OFF_W1H + 524288ull;
  const size_t NEED = OFF_W1L + 524288ull;          // ~513.5MB

  const int ntiles = (MM / 128) * (HH / 128);  // 4096

  if (ws_size >= NEED) {
    unsigned short* A1h = (unsigned short*)(wsb + OFF_A1H);
    unsigned short* A1l = (unsigned short*)(wsb + OFF_A1L);
    unsigned short* W0h = (unsigned short*)(wsb + OFF_W0H);
    unsigned short* W0l = (unsigned short*)(wsb + OFF_W0L);
    unsigned short* W1h = (unsigned short*)(wsb + OFF_W1H);
    unsigned short* W1l = (unsigned short*)(wsb + OFF_W1L);

    convert_w<<<(HH * II) / 256, 256, 0, stream>>>(w_ih0, W0h, W0l, HH * II);
    convert_w<<<(HH * HH) / 256, 256, 0, stream>>>(w_ih1, W1h, W1l, HH * HH);
    gemm_mfma<II, 1><<<ntiles, 256, 0, stream>>>(x, nullptr, nullptr, nullptr, W0h, W0l, b_ih0, pre0);
    indrnn_scan2<true><<<(BB * HH) / 64, 64, 0, stream>>>(pre0, w_hh0, nullptr, A1h, A1l);
    gemm_mfma<HH, 2><<<ntiles, 256, 0, stream>>>(nullptr, A1h, A1l, nullptr, W1h, W1l, b_ih1, out);
    indrnn_scan2<false><<<(BB * HH) / 64, 64, 0, stream>>>(out, w_hh1, out, nullptr, nullptr);
  } else {
    gemm_mfma<II, 0><<<ntiles, 256, 0, stream>>>(x, nullptr, nullptr, w_ih0, nullptr, nullptr, b_ih0, pre0);
    indrnn_scan2<false><<<(BB * HH) / 64, 64, 0, stream>>>(pre0, w_hh0, pre0, nullptr, nullptr);
    gemm_mfma<HH, 0><<<ntiles, 256, 0, stream>>>(pre0, nullptr, nullptr, w_ih1, nullptr, nullptr, b_ih1, out);
    indrnn_scan2<false><<<(BB * HH) / 64, 64, 0, stream>>>(out, w_hh1, out, nullptr, nullptr);
  }
}